// Round 19
// baseline (9852.782 us; speedup 1.0000x reference)
//
#include <hip/hip_runtime.h>
#include <hip/hip_bf16.h>
#include <hip/hip_cooperative_groups.h>
#include <math.h>

namespace cg = cooperative_groups;

// Problem constants
#define Bb 16
#define Nn 64
#define Dd 4
#define Tt 40
#define Ll 10
#define Hh 128
#define Kk 4
#define Ee (Nn*(Nn-1))   // 4032
#define BNH (Bb*Nn*Hh)   // 131072
#define SIGMA 2.8853900817779268f   // 2*log2(e): tanh(x)=1-2/(exp2(SIGMA*x)+1)

typedef __attribute__((ext_vector_type(8))) short short8;
typedef __attribute__((ext_vector_type(4))) float f32x4;

#define AS1 __attribute__((address_space(1)))
#define AS3 __attribute__((address_space(3)))

__device__ __forceinline__ float tanhE(float y){
    float e = __builtin_amdgcn_exp2f(y);
    float r = __builtin_amdgcn_rcpf(e + 1.0f);
    return fmaf(-2.0f, r, 1.0f);
}
__device__ __forceinline__ float tanh_fast(float x){ return tanhE(SIGMA * x); }
__device__ __forceinline__ float sigmoid_fast(float x){
    return __builtin_amdgcn_rcpf(1.0f + __expf(-x));
}
__device__ __forceinline__ unsigned short f2bf(float x){   // RNE f32->bf16
    unsigned int u = __float_as_uint(x);
    return (unsigned short)((u + 0x7FFFu + ((u >> 16) & 1u)) >> 16);
}
__device__ __forceinline__ unsigned int pack_bf2(float lo, float hi){
    union { __hip_bfloat162 h; unsigned int u; } cv;
    cv.h = __float22bfloat162_rn(make_float2(lo, hi));
    return cv.u;
}
__device__ __forceinline__ void g2lds16(const void* g, void* l){
    __builtin_amdgcn_global_load_lds((const AS1 unsigned int*)g,
                                     (AS3 unsigned int*)l, 16, 0, 0);
}

// ---------------------------------------------------------------------------
// Precompute: W2 -> bf16 B-frag layout (blocks 0..31); b2l = SIGMA*b2 (blk 32)
// ---------------------------------------------------------------------------
__global__ void __launch_bounds__(256) kW2f(const float* __restrict__ W2,
                                            const float* __restrict__ b2,
                                            unsigned short* __restrict__ W2f,
                                            float* __restrict__ b2l){
    if (blockIdx.x == 32){
        int i = threadIdx.x;
        b2l[i]       = SIGMA * b2[i];
        b2l[i + 256] = SIGMA * b2[i + 256];
        return;
    }
    int t    = blockIdx.x * 256 + threadIdx.x;   // 0..8191
    int lane = t & 63;
    int nt   = (t >> 6) & 7;
    int kc   = (t >> 9) & 3;
    int k    = (t >> 11) & 3;
    int col  = nt * 16 + (lane & 15);
    int fb   = kc * 32 + (lane >> 4) * 8;
    unsigned int w[4];
#pragma unroll
    for (int p = 0; p < 4; ++p){
        unsigned short lo = f2bf(W2[(k*Hh + fb + 2*p    )*Hh + col]);
        unsigned short hi = f2bf(W2[(k*Hh + fb + 2*p + 1)*Hh + col]);
        w[p] = (unsigned int)lo | ((unsigned int)hi << 16);
    }
    ((uint4*)W2f)[t] = make_uint4(w[0], w[1], w[2], w[3]);
}

// ---------------------------------------------------------------------------
// Precompute: W1 -> bf16 B-frag layout.  64 blocks x 256 threads.
// ---------------------------------------------------------------------------
__global__ void __launch_bounds__(256) kW1f(const float* __restrict__ W1,
                                            unsigned short* __restrict__ W1f){
    int t    = blockIdx.x * 256 + threadIdx.x;   // 0..16383
    int lane = t & 63;
    int nt   = (t >> 6) & 7;
    int kc   = (t >> 9) & 3;
    int s    = t >> 11;                          // 0..7
    int col  = nt * 16 + (lane & 15);
    int fb   = kc * 32 + (lane >> 4) * 8;
    unsigned int w[4];
#pragma unroll
    for (int p = 0; p < 4; ++p){
        unsigned short lo = f2bf(W1[(size_t)(s*Hh + fb + 2*p    )*Hh + col]);
        unsigned short hi = f2bf(W1[(size_t)(s*Hh + fb + 2*p + 1)*Hh + col]);
        w[p] = (unsigned int)lo | ((unsigned int)hi << 16);
    }
    ((uint4*)W1f)[t] = make_uint4(w[0], w[1], w[2], w[3]);
}

// ---------------------------------------------------------------------------
// kMega: persistent cooperative kernel — full 50-step recurrence.
// 256 blocks x 512 thr (1 block/CU guaranteed -> coop launch always valid).
// blk = k*64 + b*4 + np  (k=blk>>6, b=(blk>>2)&15, np=blk&3).
// XCD = blk%8 = (b*4+np)%8, independent of k -> phase-C aggp reads are local.
// Phase B: GEMM1 (Sf, swizzled sfs) + GEMM2 (Mtile np -> 16 rrs rows);
//          message loop x2 rounds (receivers np*16 + rr*8 + wave).
// Phase C: nodes bn0C..+3 = b*64 + np*16 + k*4 + {0..3}: agg sum, GRU,
//          MLP (4-way f-split), pred, hbf.  grid.sync between phases.
// w2s / rel_s / b2s staged ONCE.
// ---------------------------------------------------------------------------
__global__ void __launch_bounds__(512, 2) kMega(
    unsigned short* hbf, const unsigned short* __restrict__ W1f,
    const unsigned short* __restrict__ W2f,
    const float* __restrict__ b1, const float* __restrict__ b2l,
    const float* __restrict__ rel, float* aggp,
    const float* __restrict__ data, float* hidden, float* prevpred,
    const float* __restrict__ Wr_in, const float* __restrict__ br_in,
    const float* __restrict__ Wi_in, const float* __restrict__ bi_in,
    const float* __restrict__ Wn_in, const float* __restrict__ bn_in,
    const float* __restrict__ Wr_h,  const float* __restrict__ Wi_h,
    const float* __restrict__ Wh_h,
    const float* __restrict__ Wo1,   const float* __restrict__ bo1,
    const float* __restrict__ Wo2,   const float* __restrict__ bo2,
    const float* __restrict__ Wo3,   const float* __restrict__ bo3,
    float* out)
{
    __shared__ unsigned short w2s[32*512];   // 32KB, persistent
    __shared__ float rel_s[16][64];          // 4KB, persistent
    __shared__ float b2s[Hh];                // 0.5KB, persistent
    __shared__ float scratch[10240];         // 40KB: B: sfs[8192]+rrs[2048]; C overlay

    cg::grid_group grid = cg::this_grid();

    const int blk  = blockIdx.x;
    const int k    = blk >> 6;
    const int b    = (blk >> 2) & 15;
    const int np   = blk & 3;
    const int tid  = threadIdx.x;
    const int wave = tid >> 6;
    const int lane = tid & 63;
    const int colb  = lane & 15;
    const int rbase = (lane >> 4) << 2;

    // ======== one-time staging (t-invariant) ========
    {
        const uint4* src = (const uint4*)(W2f + (size_t)k*16384);
        uint4* dst = (uint4*)w2s;
#pragma unroll
        for (int i = 0; i < 4; ++i)
            g2lds16(src + tid + i*512, dst + tid + i*512);
    }
#pragma unroll
    for (int idx = tid; idx < 1024; idx += 512){   // rel by SENDER, 16 receivers
        int ri = idx >> 6, s = idx & 63;
        int n64 = np*16 + ri;
        float w = 0.0f;
        if (s != n64){
            int e = s - (s > n64);
            w = rel[(b*Ee + n64*63 + e)*Kk + k];
        }
        rel_s[ri][s] = w;
    }
    if (tid < 128) b2s[tid] = b2l[k*Hh + tid];
    __syncthreads();

    const short8* hv  = (const short8*)hbf;   // [b][Mt][kc][lane]
    const short8* wv  = (const short8*)W1f;   // [s][kc][nt][lane]
    const short8* w2v = (const short8*)w2s;

    float* sfs = scratch;            // 8192 floats (32KB), swizzled
    float* rrs = scratch + 8192;     // 2048 floats (8KB): [16 rows][128]

    // phase-C scratch overlay
    float* aggL = scratch;           // [4][128]
    float* bufL = scratch + 512;     // [4][128]
    float* insL = scratch + 1024;    // [4][4] (pad 64)
    float* psh  = scratch + 1088;    // [3][3][4][128] = 4608 floats

    const int bn0C = b*64 + np*16 + k*4;    // phase-C nodes: bn0C..+3
    const int hC   = tid & 127;
    const int fq   = tid >> 7;              // f-quarter 0..3
    const int f0   = fq * 32;

#pragma unroll 1
    for (int t = 0; t < Tt + Ll; ++t){
        // =================== phase B ===================
        // ---- GEMM1: Sf k-slice (all 64 nodes) -> sfs swizzled ----
        {
            const int mt  = wave >> 1;
            const int nt0 = (wave & 1) * 4;
            short8 a[4];
#pragma unroll
            for (int kc = 0; kc < 4; ++kc)
                a[kc] = hv[((size_t)((b*4 + mt)*4) + kc)*64 + lane];
            f32x4 acc[4];
#pragma unroll
            for (int j = 0; j < 4; ++j) acc[j] = (f32x4)0.0f;
#pragma unroll
            for (int kc = 0; kc < 4; ++kc){
#pragma unroll
                for (int j = 0; j < 4; ++j){
                    short8 bf = wv[((size_t)((2*k)*4 + kc)*8 + nt0 + j)*64 + lane];
                    acc[j] = __builtin_amdgcn_mfma_f32_16x16x32_bf16(a[kc], bf, acc[j], 0, 0, 0);
                }
            }
            char* sfsB = (char*)sfs;
#pragma unroll
            for (int j = 0; j < 4; ++j){
                int h  = (nt0 + j)*16 + colb;
                int fg = h >> 3, fl = h & 7;
                int sw = (fg & 7) << 4;
#pragma unroll
                for (int r = 0; r < 4; ++r){
                    int node = mt*16 + rbase + r;
                    int A = fg*2048 + node*32 + fl*4;
                    *(float*)(sfsB + (A ^ sw)) = SIGMA * acc[j][r];
                }
            }
        }
        // ---- GEMM2: Rr Mtile np (16 rows) -> rrs; wave w = ntile w ----
        {
            short8 a[4];
#pragma unroll
            for (int kc = 0; kc < 4; ++kc)
                a[kc] = hv[((size_t)((b*4 + np)*4) + kc)*64 + lane];
            f32x4 acc = (f32x4)0.0f;
#pragma unroll
            for (int kc = 0; kc < 4; ++kc){
                short8 bf = wv[((size_t)((2*k+1)*4 + kc)*8 + wave)*64 + lane];
                acc = __builtin_amdgcn_mfma_f32_16x16x32_bf16(a[kc], bf, acc, 0, 0, 0);
            }
            const int h   = wave*16 + colb;
            const float b1v = b1[k*Hh + h];
#pragma unroll
            for (int r = 0; r < 4; ++r)
                rrs[(rbase + r)*Hh + h] = SIGMA * (acc[r] + b1v);
        }
        __syncthreads();   // sfs/rrs written

        // ---- message loop: 2 rounds, receiver = np*16 + rr*8 + wave ----
#pragma unroll 1
        for (int rr = 0; rr < 2; ++rr){
            const int ri   = rr*8 + wave;        // 0..15 within block
            const int n64  = np*16 + ri;
            const int fo   = lane >> 4;
            const int srow = lane & 15;
            const char* sfsB = (const char*)sfs;
            const float* rrw = rrs + ri*Hh;
            const float* relw = rel_s[ri];

            float aggacc[8];
#pragma unroll
            for (int nt = 0; nt < 8; ++nt) aggacc[nt] = 0.0f;

#pragma unroll 1
            for (int st = 0; st < 4; ++st){
                short8 a[4];
#pragma unroll
                for (int kc = 0; kc < 4; ++kc){
                    const int fg = kc*4 + fo;
                    const int A  = fg*2048 + (st*16 + srow)*32;
                    const int sw = (fg & 7) << 4;
                    float4 s0 = *(const float4*)(sfsB + (A ^ sw));
                    float4 s1 = *(const float4*)(sfsB + ((A + 16) ^ sw));
                    const float4* rp = (const float4*)(rrw + fg*8);
                    float4 r0 = rp[0], r1 = rp[1];
                    union { short8 v; unsigned int u[4]; } av;
                    av.u[0] = pack_bf2(tanhE(s0.x+r0.x), tanhE(s0.y+r0.y));
                    av.u[1] = pack_bf2(tanhE(s0.z+r0.z), tanhE(s0.w+r0.w));
                    av.u[2] = pack_bf2(tanhE(s1.x+r1.x), tanhE(s1.y+r1.y));
                    av.u[3] = pack_bf2(tanhE(s1.z+r1.z), tanhE(s1.w+r1.w));
                    a[kc] = av.v;
                }

                f32x4 acc[8];
#pragma unroll
                for (int nt = 0; nt < 8; ++nt) acc[nt] = (f32x4)0.0f;
#pragma unroll
                for (int kc = 0; kc < 4; ++kc){
#pragma unroll
                    for (int nt = 0; nt < 8; ++nt){
                        short8 bfr = w2v[(kc*8 + nt)*64 + lane];
                        acc[nt] = __builtin_amdgcn_mfma_f32_16x16x32_bf16(a[kc], bfr, acc[nt], 0, 0, 0);
                    }
                }

#pragma unroll
                for (int nt = 0; nt < 8; ++nt){
                    float bv = b2s[nt*16 + colb];
                    float s = 0.0f;
#pragma unroll
                    for (int r = 0; r < 4; ++r)
                        s = fmaf(relw[st*16 + rbase + r], tanhE(fmaf(SIGMA, acc[nt][r], bv)), s);
                    s += __shfl_xor(s, 16);
                    s += __shfl_xor(s, 32);
                    aggacc[nt] += s;
                }
            }

            if (lane < 16){
                const int bn = b*64 + n64;
#pragma unroll
                for (int nt = 0; nt < 8; ++nt)
                    aggp[((size_t)bn*4 + k)*Hh + nt*16 + lane] = aggacc[nt];
            }
        }
        __threadfence();
        grid.sync();

        // =================== phase C (4 nodes) ===================
        {
            int g = tid >> 7;
            const float* ap = aggp + ((size_t)(bn0C + g)*4)*Hh + hC;
            aggL[g*Hh + hC] = (ap[0] + ap[Hh] + ap[2*Hh] + ap[3*Hh]) * (1.0f/16.0f);
        }
        if (tid < 16){
            int g = tid >> 2, d = tid & 3;
            int bn = bn0C + g;
            insL[g*4 + d] = (t < Tt) ? data[(bn*Dd + d)*Tt + t] : prevpred[bn*Dd + d];
        }
        __syncthreads();

        // gate hidden GEMVs, 4-way f-split, 4 nodes
        float rh[4] = {0,0,0,0}, ih[4] = {0,0,0,0}, hh[4] = {0,0,0,0};
        for (int f = f0; f < f0 + 32; ++f){
            float wr = Wr_h[f*Hh + hC], wi = Wi_h[f*Hh + hC], wh = Wh_h[f*Hh + hC];
#pragma unroll
            for (int g = 0; g < 4; ++g){
                float av = aggL[g*Hh + f];
                rh[g] += av*wr; ih[g] += av*wi; hh[g] += av*wh;
            }
        }
        if (fq){
#pragma unroll
            for (int g = 0; g < 4; ++g){
                psh[(((fq-1)*3 + 0)*4 + g)*Hh + hC] = rh[g];
                psh[(((fq-1)*3 + 1)*4 + g)*Hh + hC] = ih[g];
                psh[(((fq-1)*3 + 2)*4 + g)*Hh + hC] = hh[g];
            }
        }
        __syncthreads();

        if (!fq){
            const float wr0 = Wr_in[hC],        wr1 = Wr_in[Hh + hC],
                        wr2 = Wr_in[2*Hh + hC], wr3 = Wr_in[3*Hh + hC];
            const float wi0 = Wi_in[hC],        wi1 = Wi_in[Hh + hC],
                        wi2 = Wi_in[2*Hh + hC], wi3 = Wi_in[3*Hh + hC];
            const float wn0 = Wn_in[hC],        wn1 = Wn_in[Hh + hC],
                        wn2 = Wn_in[2*Hh + hC], wn3 = Wn_in[3*Hh + hC];
            const float brv = br_in[hC], biv = bi_in[hC], bnv = bn_in[hC];
            const int kcx = hC >> 5;
            const int lhi = (hC >> 3) & 3;
            const int jj  = hC & 7;
#pragma unroll
            for (int g = 0; g < 4; ++g){
                float rs = rh[g], is = ih[g], hs = hh[g];
#pragma unroll
                for (int q = 0; q < 3; ++q){
                    rs += psh[((q*3 + 0)*4 + g)*Hh + hC];
                    is += psh[((q*3 + 1)*4 + g)*Hh + hC];
                    hs += psh[((q*3 + 2)*4 + g)*Hh + hC];
                }
                float i0 = insL[g*4+0], i1 = insL[g*4+1], i2 = insL[g*4+2], i3 = insL[g*4+3];
                float r  = sigmoid_fast(brv + i0*wr0 + i1*wr1 + i2*wr2 + i3*wr3 + rs);
                float ii = sigmoid_fast(biv + i0*wi0 + i1*wi1 + i2*wi2 + i3*wi3 + is);
                float nn = tanh_fast   (bnv + i0*wn0 + i1*wn1 + i2*wn2 + i3*wn3 + r*hs);
                float hold = hidden[(bn0C+g)*Hh + hC];
                float hnew = (1.0f - ii)*nn + ii*hold;
                hidden[(bn0C+g)*Hh + hC] = hnew;
                bufL[g*Hh + hC] = hnew;
                int bn   = bn0C + g;
                int bb   = bn >> 6, node64 = bn & 63;
                int Mt   = node64 >> 4;
                int lane2 = (node64 & 15) + lhi*16;
                hbf[((size_t)((bb*4 + Mt)*4 + kcx)*64 + lane2)*8 + jj] = f2bf(hnew);
            }
        }
        __syncthreads();

        // y1 = relu(hnew @ Wo1 + bo1)
        {
            float yp[4] = {0,0,0,0};
            for (int f = f0; f < f0 + 32; ++f){
                float wv1 = Wo1[f*Hh + hC];
#pragma unroll
                for (int g = 0; g < 4; ++g) yp[g] += bufL[g*Hh + f]*wv1;
            }
            if (fq){
#pragma unroll
                for (int g = 0; g < 4; ++g) psh[(((fq-1)*3)*4 + g)*Hh + hC] = yp[g];
            }
            __syncthreads();
            if (!fq){
                float b1v = bo1[hC];
#pragma unroll
                for (int g = 0; g < 4; ++g)
                    bufL[g*Hh + hC] = fmaxf(b1v + yp[g] + psh[(0*4+g)*Hh + hC]
                                            + psh[(12+g)*Hh + hC] + psh[(24+g)*Hh + hC], 0.0f);
            }
        }
        __syncthreads();

        // y2 = relu(y1 @ Wo2 + bo2)
        {
            float yp[4] = {0,0,0,0};
            for (int f = f0; f < f0 + 32; ++f){
                float wv2 = Wo2[f*Hh + hC];
#pragma unroll
                for (int g = 0; g < 4; ++g) yp[g] += bufL[g*Hh + f]*wv2;
            }
            if (fq){
#pragma unroll
                for (int g = 0; g < 4; ++g) psh[(((fq-1)*3)*4 + g)*Hh + hC] = yp[g];
            }
            __syncthreads();
            if (!fq){
                float b2v = bo2[hC];
#pragma unroll
                for (int g = 0; g < 4; ++g)
                    bufL[g*Hh + hC] = fmaxf(b2v + yp[g] + psh[(0*4+g)*Hh + hC]
                                            + psh[(12+g)*Hh + hC] + psh[(24+g)*Hh + hC], 0.0f);
            }
        }
        __syncthreads();

        // pred = ins + y2 @ Wo3 + bo3
        if (tid < 16){
            int g = tid >> 2, d = tid & 3;
            float pv = bo3[d];
            for (int f = 0; f < Hh; ++f) pv += bufL[g*Hh + f]*Wo3[f*Dd + d];
            pv += insL[g*4 + d];
            int bn = bn0C + g;
            prevpred[bn*Dd + d] = pv;
            if (t >= Tt) out[(bn*Dd + d)*Ll + (t - Tt)] = pv;
        }
        __threadfence();
        grid.sync();
    }
}

// ---------------------------------------------------------------------------
extern "C" void kernel_launch(void* const* d_in, const int* in_sizes, int n_in,
                              void* d_out, int out_size, void* d_ws, size_t ws_size,
                              hipStream_t stream){
    const float* data  = (const float*)d_in[0];
    const float* rel   = (const float*)d_in[1];
    const float* W1    = (const float*)d_in[2];
    const float* b1    = (const float*)d_in[3];
    const float* W2    = (const float*)d_in[4];
    const float* b2    = (const float*)d_in[5];
    const float* Wr_h  = (const float*)d_in[6];
    const float* Wi_h  = (const float*)d_in[7];
    const float* Wh_h  = (const float*)d_in[8];
    const float* Wr_in = (const float*)d_in[9];
    const float* br_in = (const float*)d_in[10];
    const float* Wi_in = (const float*)d_in[11];
    const float* bi_in = (const float*)d_in[12];
    const float* Wn_in = (const float*)d_in[13];
    const float* bn_in = (const float*)d_in[14];
    const float* Wo1   = (const float*)d_in[15];
    const float* bo1   = (const float*)d_in[16];
    const float* Wo2   = (const float*)d_in[17];
    const float* bo2   = (const float*)d_in[18];
    const float* Wo3   = (const float*)d_in[19];
    const float* bo3   = (const float*)d_in[20];

    float* out = (float*)d_out;
    float* ws  = (float*)d_ws;

    // workspace: hidden | prevpred | hbf(bf16) | aggp | W2f | b2l | W1f
    float* hidden   = ws;                              // 131072 f
    float* prevpred = hidden + BNH;                    // 4096 f
    unsigned short* hbf = (unsigned short*)(prevpred + Bb*Nn*Dd);  // 131072 us
    float* aggp     = (float*)(hbf + BNH);             // 4*131072 f  [bn][k][h]
    unsigned short* W2f = (unsigned short*)(aggp + 4*BNH);   // 65536 us
    float* b2l      = (float*)(W2f + 65536);           // 512 f
    unsigned short* W1f = (unsigned short*)(b2l + 512);      // 131072 us

    // hidden, prevpred, hbf carry state across steps -> zero every launch
    hipMemsetAsync(hidden, 0, (size_t)(Bb*Nn*Hh + Bb*Nn*Dd)*4 + (size_t)BNH*2, stream);
    kW2f<<<33, 256, 0, stream>>>(W2, b2, W2f, b2l);
    kW1f<<<64, 256, 0, stream>>>(W1, W1f);

    // cooperative mega-kernel: the whole 50-step recurrence in one launch
    void* a_hbf = (void*)hbf;      void* a_W1f = (void*)W1f;
    void* a_W2f = (void*)W2f;      void* a_b1  = (void*)b1;
    void* a_b2l = (void*)b2l;      void* a_rel = (void*)rel;
    void* a_agg = (void*)aggp;     void* a_dat = (void*)data;
    void* a_hid = (void*)hidden;   void* a_pp  = (void*)prevpred;
    void* a_wr  = (void*)Wr_in;    void* a_brr = (void*)br_in;
    void* a_wi  = (void*)Wi_in;    void* a_bi  = (void*)bi_in;
    void* a_wn  = (void*)Wn_in;    void* a_bn  = (void*)bn_in;
    void* a_wrh = (void*)Wr_h;     void* a_wih = (void*)Wi_h;
    void* a_whh = (void*)Wh_h;
    void* a_wo1 = (void*)Wo1;      void* a_bo1 = (void*)bo1;
    void* a_wo2 = (void*)Wo2;      void* a_bo2 = (void*)bo2;
    void* a_wo3 = (void*)Wo3;      void* a_bo3 = (void*)bo3;
    void* a_out = (void*)out;
    void* args[] = { &a_hbf, &a_W1f, &a_W2f, &a_b1, &a_b2l, &a_rel, &a_agg,
                     &a_dat, &a_hid, &a_pp,
                     &a_wr, &a_brr, &a_wi, &a_bi, &a_wn, &a_bn,
                     &a_wrh, &a_wih, &a_whh,
                     &a_wo1, &a_bo1, &a_wo2, &a_bo2, &a_wo3, &a_bo3, &a_out };
    hipLaunchCooperativeKernel((void*)kMega, dim3(256), dim3(512), args, 0, stream);
}

// Round 20
// 1947.897 us; speedup vs baseline: 5.0582x; 5.0582x over previous
//
#include <hip/hip_runtime.h>
#include <hip/hip_bf16.h>
#include <math.h>

// Problem constants
#define Bb 16
#define Nn 64
#define Dd 4
#define Tt 40
#define Ll 10
#define Hh 128
#define Kk 4
#define Ee (Nn*(Nn-1))   // 4032
#define BNH (Bb*Nn*Hh)   // 131072
#define SIGMA 2.8853900817779268f   // 2*log2(e): tanh(x)=1-2/(exp2(SIGMA*x)+1)

typedef __attribute__((ext_vector_type(8))) short short8;
typedef __attribute__((ext_vector_type(4))) float f32x4;

#define AS1 __attribute__((address_space(1)))
#define AS3 __attribute__((address_space(3)))

// tanh from PRE-SCALED argument y = SIGMA*x:  tanh(x) = 1 - 2/(exp2(y)+1)
__device__ __forceinline__ float tanhE(float y){
    float e = __builtin_amdgcn_exp2f(y);
    float r = __builtin_amdgcn_rcpf(e + 1.0f);
    return fmaf(-2.0f, r, 1.0f);
}
__device__ __forceinline__ float tanh_fast(float x){ return tanhE(SIGMA * x); }
__device__ __forceinline__ float sigmoid_fast(float x){
    return __builtin_amdgcn_rcpf(1.0f + __expf(-x));
}
__device__ __forceinline__ unsigned short f2bf(float x){   // RNE f32->bf16
    unsigned int u = __float_as_uint(x);
    return (unsigned short)((u + 0x7FFFu + ((u >> 16) & 1u)) >> 16);
}
// packed RNE f32x2 -> bf16x2 (v_cvt_pk_bf16_f32)
__device__ __forceinline__ unsigned int pack_bf2(float lo, float hi){
    union { __hip_bfloat162 h; unsigned int u; } cv;
    cv.h = __float22bfloat162_rn(make_float2(lo, hi));
    return cv.u;
}
// async global->LDS, 16B per lane
__device__ __forceinline__ void g2lds16(const void* g, void* l){
    __builtin_amdgcn_global_load_lds((const AS1 unsigned int*)g,
                                     (AS3 unsigned int*)l, 16, 0, 0);
}

// ---------------------------------------------------------------------------
// Precompute: W2 -> bf16 B-frag layout (blocks 0..31); b2l = SIGMA*b2 (blk 32)
// ---------------------------------------------------------------------------
__global__ void __launch_bounds__(256) kW2f(const float* __restrict__ W2,
                                            const float* __restrict__ b2,
                                            unsigned short* __restrict__ W2f,
                                            float* __restrict__ b2l){
    if (blockIdx.x == 32){
        int i = threadIdx.x;
        b2l[i]       = SIGMA * b2[i];
        b2l[i + 256] = SIGMA * b2[i + 256];
        return;
    }
    int t    = blockIdx.x * 256 + threadIdx.x;   // 0..8191
    int lane = t & 63;
    int nt   = (t >> 6) & 7;
    int kc   = (t >> 9) & 3;
    int k    = (t >> 11) & 3;
    int col  = nt * 16 + (lane & 15);
    int fb   = kc * 32 + (lane >> 4) * 8;
    unsigned int w[4];
#pragma unroll
    for (int p = 0; p < 4; ++p){
        unsigned short lo = f2bf(W2[(k*Hh + fb + 2*p    )*Hh + col]);
        unsigned short hi = f2bf(W2[(k*Hh + fb + 2*p + 1)*Hh + col]);
        w[p] = (unsigned int)lo | ((unsigned int)hi << 16);
    }
    ((uint4*)W2f)[t] = make_uint4(w[0], w[1], w[2], w[3]);
}

// ---------------------------------------------------------------------------
// Precompute: W1 -> bf16 B-frag layout.  64 blocks x 256 threads.
// ---------------------------------------------------------------------------
__global__ void __launch_bounds__(256) kW1f(const float* __restrict__ W1,
                                            unsigned short* __restrict__ W1f){
    int t    = blockIdx.x * 256 + threadIdx.x;   // 0..16383
    int lane = t & 63;
    int nt   = (t >> 6) & 7;
    int kc   = (t >> 9) & 3;
    int s    = t >> 11;                          // 0..7
    int col  = nt * 16 + (lane & 15);
    int fb   = kc * 32 + (lane >> 4) * 8;
    unsigned int w[4];
#pragma unroll
    for (int p = 0; p < 4; ++p){
        unsigned short lo = f2bf(W1[(size_t)(s*Hh + fb + 2*p    )*Hh + col]);
        unsigned short hi = f2bf(W1[(size_t)(s*Hh + fb + 2*p + 1)*Hh + col]);
        w[p] = (unsigned int)lo | ((unsigned int)hi << 16);
    }
    ((uint4*)W1f)[t] = make_uint4(w[0], w[1], w[2], w[3]);
}

// ---------------------------------------------------------------------------
// Kernel B (fused SR-GEMM prologue + message MFMA).
// blk = k*128 + b*8 + no  ->  XCD(blk%8) = no for ALL k of a given (b,no):
// the 4 k-partials of each node are written from the SAME XCD (kC reads local).
// aggp layout: [bn][k][h] (node's 4 partials contiguous, 2KB).
// ---------------------------------------------------------------------------
__global__ void __launch_bounds__(512, 2) kB(const unsigned short* __restrict__ hbf,
                                             const unsigned short* __restrict__ W1f,
                                             const unsigned short* __restrict__ W2f,
                                             const float* __restrict__ b1,
                                             const float* __restrict__ b2l,
                                             const float* __restrict__ rel,
                                             float* __restrict__ aggp){
    __shared__ unsigned short w2s[32*512];   // 32KB
    __shared__ float sfs[8192];              // 32KB, swizzled
    __shared__ float rrs[8*Hh];              // 4KB
    __shared__ float rel_s[8][64];           // 2KB
    __shared__ float b2s[Hh];                // 0.5KB

    const int blk  = blockIdx.x;
    const int k    = blk >> 7;
    const int rem  = blk & 127;
    const int b    = rem >> 3;
    const int no   = rem & 7;
    const int tid  = threadIdx.x;
    const int wave = tid >> 6;
    const int lane = tid & 63;

    // ---- async stage W2f k-slice (in flight during prologue GEMMs) ----
    {
        const uint4* src = (const uint4*)(W2f + (size_t)k*16384);
        uint4* dst = (uint4*)w2s;
#pragma unroll
        for (int i = 0; i < 4; ++i)
            g2lds16(src + tid + i*512, dst + tid + i*512);
    }
    {   // rel by SENDER: rel_s[g][s]; self -> 0
        int g = tid >> 6, s = tid & 63;
        int n = no*8 + g;
        float w = 0.0f;
        if (s != n){
            int e = s - (s > n);
            w = rel[(b*Ee + n*63 + e)*Kk + k];
        }
        rel_s[g][s] = w;
    }
    if (tid < 128) b2s[tid] = b2l[k*Hh + tid];

    const short8* hv = (const short8*)hbf;   // [b][Mt][kc][lane]
    const short8* wv = (const short8*)W1f;   // [s][kc][nt][lane]
    const int colb  = lane & 15;
    const int rbase = (lane >> 4) << 2;

    // ---- GEMM1: Sf k-slice -> sfs (wave w: Mtile w>>1, ntiles (w&1)*4..) ----
    {
        const int mt  = wave >> 1;
        const int nt0 = (wave & 1) * 4;
        short8 a[4];
#pragma unroll
        for (int kc = 0; kc < 4; ++kc)
            a[kc] = hv[((size_t)((b*4 + mt)*4) + kc)*64 + lane];
        f32x4 acc[4];
#pragma unroll
        for (int j = 0; j < 4; ++j) acc[j] = (f32x4)0.0f;
#pragma unroll
        for (int kc = 0; kc < 4; ++kc){
#pragma unroll
            for (int j = 0; j < 4; ++j){
                short8 bf = wv[((size_t)((2*k)*4 + kc)*8 + nt0 + j)*64 + lane];
                acc[j] = __builtin_amdgcn_mfma_f32_16x16x32_bf16(a[kc], bf, acc[j], 0, 0, 0);
            }
        }
        char* sfsB = (char*)sfs;
#pragma unroll
        for (int j = 0; j < 4; ++j){
            int h  = (nt0 + j)*16 + colb;
            int fg = h >> 3, fl = h & 7;
            int sw = (fg & 7) << 4;
#pragma unroll
            for (int r = 0; r < 4; ++r){
                int node = mt*16 + rbase + r;
                int A = fg*2048 + node*32 + fl*4;
                *(float*)(sfsB + (A ^ sw)) = SIGMA * acc[j][r];
            }
        }
    }
    // ---- GEMM2: Rr rows no*8..+8 -> rrs (wave w: ntile w) ----
    {
        const int mtr = no >> 1;
        short8 a[4];
#pragma unroll
        for (int kc = 0; kc < 4; ++kc)
            a[kc] = hv[((size_t)((b*4 + mtr)*4) + kc)*64 + lane];
        f32x4 acc = (f32x4)0.0f;
#pragma unroll
        for (int kc = 0; kc < 4; ++kc){
            short8 bf = wv[((size_t)((2*k+1)*4 + kc)*8 + wave)*64 + lane];
            acc = __builtin_amdgcn_mfma_f32_16x16x32_bf16(a[kc], bf, acc, 0, 0, 0);
        }
        const int h   = wave*16 + colb;
        const float b1v = b1[k*Hh + h];
        const int lo  = (no & 1) * 8;
#pragma unroll
        for (int r = 0; r < 4; ++r){
            int row = rbase + r;            // 0..15 within Mtile
            if (row >= lo && row < lo + 8)
                rrs[(row - lo)*Hh + h] = SIGMA * (acc[r] + b1v);
        }
    }
    __syncthreads();   // sfs/rrs written + w2s async loads drained — LAST barrier

    const int n    = no*8 + wave;        // this wave's receiver
    const int fo   = lane >> 4;          // f-octet 0..3
    const int srow = lane & 15;          // sender within strip
    const char* sfsB = (const char*)sfs;
    const float* rrw = rrs + wave*Hh;
    const short8* w2v = (const short8*)w2s;
    const float* relw = rel_s[wave];

    float aggacc[8];
#pragma unroll
    for (int nt = 0; nt < 8; ++nt) aggacc[nt] = 0.0f;

#pragma unroll 1
    for (int st = 0; st < 4; ++st){
        // ---- A-build from LDS (swizzled Sf reads, broadcast Rr reads) ----
        short8 a[4];
#pragma unroll
        for (int kc = 0; kc < 4; ++kc){
            const int fg = kc*4 + fo;
            const int A  = fg*2048 + (st*16 + srow)*32;
            const int sw = (fg & 7) << 4;
            float4 s0 = *(const float4*)(sfsB + (A ^ sw));
            float4 s1 = *(const float4*)(sfsB + ((A + 16) ^ sw));
            const float4* rp = (const float4*)(rrw + fg*8);
            float4 r0 = rp[0], r1 = rp[1];
            union { short8 v; unsigned int u[4]; } av;
            av.u[0] = pack_bf2(tanhE(s0.x+r0.x), tanhE(s0.y+r0.y));
            av.u[1] = pack_bf2(tanhE(s0.z+r0.z), tanhE(s0.w+r0.w));
            av.u[2] = pack_bf2(tanhE(s1.x+r1.x), tanhE(s1.y+r1.y));
            av.u[3] = pack_bf2(tanhE(s1.z+r1.z), tanhE(s1.w+r1.w));
            a[kc] = av.v;
        }

        // ---- MFMA: 4 kc x 8 nt for this strip ----
        f32x4 acc[8];
#pragma unroll
        for (int nt = 0; nt < 8; ++nt) acc[nt] = (f32x4)0.0f;
#pragma unroll
        for (int kc = 0; kc < 4; ++kc){
#pragma unroll
            for (int nt = 0; nt < 8; ++nt){
                short8 bfr = w2v[(kc*8 + nt)*64 + lane];
                acc[nt] = __builtin_amdgcn_mfma_f32_16x16x32_bf16(a[kc], bfr, acc[nt], 0, 0, 0);
            }
        }

        // ---- epilogue: tanhE + rel weight, shfl reduce, accumulate ----
#pragma unroll
        for (int nt = 0; nt < 8; ++nt){
            float bv = b2s[nt*16 + colb];
            float s = 0.0f;
#pragma unroll
            for (int r = 0; r < 4; ++r)
                s = fmaf(relw[st*16 + rbase + r], tanhE(fmaf(SIGMA, acc[nt][r], bv)), s);
            s += __shfl_xor(s, 16);
            s += __shfl_xor(s, 32);
            aggacc[nt] += s;
        }
    }

    if (lane < 16){
        const int bn = b*64 + n;
#pragma unroll
        for (int nt = 0; nt < 8; ++nt)
            aggp[((size_t)bn*4 + k)*Hh + nt*16 + lane] = aggacc[nt];
    }
}

// ---------------------------------------------------------------------------
// Kernel C (2 nodes/block, 512 blocks, 256 thr f-split, XCD-matched):
// physical blk p: no = p&7, b = (p>>3)>>2, j = ((p>>3)&3) + no*4; nodes 2j,2j+1.
// Reader XCD (p%8 = no) == writer XCD of aggp for these nodes.
// ---------------------------------------------------------------------------
__global__ void __launch_bounds__(256) kC(const float* __restrict__ data,
                                          const float* __restrict__ aggp,
                                          float* __restrict__ hidden,
                                          float* __restrict__ prevpred,
                                          unsigned short* __restrict__ hbf,
                                          const float* __restrict__ Wr_in, const float* __restrict__ br_in,
                                          const float* __restrict__ Wi_in, const float* __restrict__ bi_in,
                                          const float* __restrict__ Wn_in, const float* __restrict__ bn_in,
                                          const float* __restrict__ Wr_h,  const float* __restrict__ Wi_h,
                                          const float* __restrict__ Wh_h,
                                          const float* __restrict__ Wo1,   const float* __restrict__ bo1,
                                          const float* __restrict__ Wo2,   const float* __restrict__ bo2,
                                          const float* __restrict__ Wo3,   const float* __restrict__ bo3,
                                          float* __restrict__ out, int t){
    __shared__ float aggL[2][Hh];
    __shared__ float buf[2][Hh];
    __shared__ float insL[2][Dd];
    __shared__ float psh[3][2][Hh];   // 3KB partial-sum exchange

    const int p   = blockIdx.x;
    const int no  = p & 7;
    const int m   = p >> 3;
    const int b   = m >> 2;
    const int j   = (m & 3) + no*4;
    const int bn0 = b*64 + j*2;

    const int tid = threadIdx.x;
    const int h   = tid & 127;
    const int fh  = tid >> 7;
    const int f0  = fh * 64;

    {   // agg sum: thread (g = fh, h): 4 contiguous k-partials per node
        int g = fh;
        const float* ap = aggp + ((size_t)(bn0 + g)*4)*Hh + h;
        aggL[g][h] = (ap[0] + ap[Hh] + ap[2*Hh] + ap[3*Hh]) * (1.0f/16.0f);
    }
    if (tid < 8){
        int g = tid >> 2, d = tid & 3;
        int bn = bn0 + g;
        insL[g][d] = (t < Tt) ? data[(bn*Dd + d)*Tt + t] : prevpred[bn*Dd + d];
    }
    __syncthreads();

    // ---- gate hidden GEMVs, f-split halves ----
    float rh[2] = {0,0}, ih[2] = {0,0}, hh[2] = {0,0};
    for (int f = f0; f < f0 + 64; ++f){
        float wr = Wr_h[f*Hh + h], wi = Wi_h[f*Hh + h], wh = Wh_h[f*Hh + h];
#pragma unroll
        for (int g = 0; g < 2; ++g){
            float av = aggL[g][f];
            rh[g] += av*wr; ih[g] += av*wi; hh[g] += av*wh;
        }
    }
    if (fh){
#pragma unroll
        for (int g = 0; g < 2; ++g){
            psh[0][g][h] = rh[g]; psh[1][g][h] = ih[g]; psh[2][g][h] = hh[g];
        }
    }
    __syncthreads();

    if (!fh){
        const float wr0 = Wr_in[h],        wr1 = Wr_in[Hh + h],
                    wr2 = Wr_in[2*Hh + h], wr3 = Wr_in[3*Hh + h];
        const float wi0 = Wi_in[h],        wi1 = Wi_in[Hh + h],
                    wi2 = Wi_in[2*Hh + h], wi3 = Wi_in[3*Hh + h];
        const float wn0 = Wn_in[h],        wn1 = Wn_in[Hh + h],
                    wn2 = Wn_in[2*Hh + h], wn3 = Wn_in[3*Hh + h];
        const float brv = br_in[h], biv = bi_in[h], bnv = bn_in[h];
        const int kc  = h >> 5;
        const int lhi = (h >> 3) & 3;
        const int jj  = h & 7;
#pragma unroll
        for (int g = 0; g < 2; ++g){
            float i0 = insL[g][0], i1 = insL[g][1], i2 = insL[g][2], i3 = insL[g][3];
            float r  = sigmoid_fast(brv + i0*wr0 + i1*wr1 + i2*wr2 + i3*wr3 + rh[g] + psh[0][g][h]);
            float ii = sigmoid_fast(biv + i0*wi0 + i1*wi1 + i2*wi2 + i3*wi3 + ih[g] + psh[1][g][h]);
            float nn = tanh_fast   (bnv + i0*wn0 + i1*wn1 + i2*wn2 + i3*wn3 + r*(hh[g] + psh[2][g][h]));
            float hold = hidden[(bn0+g)*Hh + h];
            float hnew = (1.0f - ii)*nn + ii*hold;
            hidden[(bn0+g)*Hh + h] = hnew;
            buf[g][h] = hnew;
            int bn   = bn0 + g;
            int bb   = bn >> 6, node64 = bn & 63;
            int Mt   = node64 >> 4;
            int lane = (node64 & 15) + lhi*16;
            hbf[((size_t)((bb*4 + Mt)*4 + kc)*64 + lane)*8 + jj] = f2bf(hnew);
        }
    }
    __syncthreads();

    // ---- y1 = relu(hnew @ Wo1 + bo1), f-split ----
    {
        float yp[2] = {0,0};
        for (int f = f0; f < f0 + 64; ++f){
            float wv1 = Wo1[f*Hh + h];
#pragma unroll
            for (int g = 0; g < 2; ++g) yp[g] += buf[g][f]*wv1;
        }
        if (fh){
#pragma unroll
            for (int g = 0; g < 2; ++g) psh[0][g][h] = yp[g];
        }
        __syncthreads();
        if (!fh){
            float b1v = bo1[h];
#pragma unroll
            for (int g = 0; g < 2; ++g) buf[g][h] = fmaxf(b1v + yp[g] + psh[0][g][h], 0.0f);
        }
    }
    __syncthreads();

    // ---- y2 = relu(y1 @ Wo2 + bo2), f-split ----
    {
        float yp[2] = {0,0};
        for (int f = f0; f < f0 + 64; ++f){
            float wv2 = Wo2[f*Hh + h];
#pragma unroll
            for (int g = 0; g < 2; ++g) yp[g] += buf[g][f]*wv2;
        }
        if (fh){
#pragma unroll
            for (int g = 0; g < 2; ++g) psh[0][g][h] = yp[g];
        }
        __syncthreads();
        if (!fh){
            float b2v = bo2[h];
#pragma unroll
            for (int g = 0; g < 2; ++g) buf[g][h] = fmaxf(b2v + yp[g] + psh[0][g][h], 0.0f);
        }
    }
    __syncthreads();

    // ---- pred = ins + y2 @ Wo3 + bo3 ----
    if (tid < 8){
        int g = tid >> 2, d = tid & 3;
        float pv = bo3[d];
        for (int f = 0; f < Hh; ++f) pv += buf[g][f]*Wo3[f*Dd + d];
        pv += insL[g][d];
        int bn = bn0 + g;
        prevpred[bn*Dd + d] = pv;
        if (t >= Tt) out[(bn*Dd + d)*Ll + (t - Tt)] = pv;
    }
}

// ---------------------------------------------------------------------------
extern "C" void kernel_launch(void* const* d_in, const int* in_sizes, int n_in,
                              void* d_out, int out_size, void* d_ws, size_t ws_size,
                              hipStream_t stream){
    const float* data  = (const float*)d_in[0];
    const float* rel   = (const float*)d_in[1];
    const float* W1    = (const float*)d_in[2];
    const float* b1    = (const float*)d_in[3];
    const float* W2    = (const float*)d_in[4];
    const float* b2    = (const float*)d_in[5];
    const float* Wr_h  = (const float*)d_in[6];
    const float* Wi_h  = (const float*)d_in[7];
    const float* Wh_h  = (const float*)d_in[8];
    const float* Wr_in = (const float*)d_in[9];
    const float* br_in = (const float*)d_in[10];
    const float* Wi_in = (const float*)d_in[11];
    const float* bi_in = (const float*)d_in[12];
    const float* Wn_in = (const float*)d_in[13];
    const float* bn_in = (const float*)d_in[14];
    const float* Wo1   = (const float*)d_in[15];
    const float* bo1   = (const float*)d_in[16];
    const float* Wo2   = (const float*)d_in[17];
    const float* bo2   = (const float*)d_in[18];
    const float* Wo3   = (const float*)d_in[19];
    const float* bo3   = (const float*)d_in[20];

    float* out = (float*)d_out;
    float* ws  = (float*)d_ws;

    // workspace: hidden | prevpred | hbf(bf16) | aggp | W2f | b2l | W1f
    float* hidden   = ws;                              // 131072 f
    float* prevpred = hidden + BNH;                    // 4096 f
    unsigned short* hbf = (unsigned short*)(prevpred + Bb*Nn*Dd);  // 131072 us
    float* aggp     = (float*)(hbf + BNH);             // 4*131072 f  [bn][k][h]
    unsigned short* W2f = (unsigned short*)(aggp + 4*BNH);   // 65536 us
    float* b2l      = (float*)(W2f + 65536);           // 512 f
    unsigned short* W1f = (unsigned short*)(b2l + 512);      // 131072 us

    // hidden, prevpred, hbf carry state across steps -> zero every launch
    hipMemsetAsync(hidden, 0, (size_t)(Bb*Nn*Hh + Bb*Nn*Dd)*4 + (size_t)BNH*2, stream);
    kW2f<<<33, 256, 0, stream>>>(W2, b2, W2f, b2l);
    kW1f<<<64, 256, 0, stream>>>(W1, W1f);

    for (int t = 0; t < Tt + Ll; ++t){
        kB<<<512, 512, 0, stream>>>(hbf, W1f, W2f, b1, b2l, rel, aggp);
        kC<<<512, 256, 0, stream>>>(data, aggp, hidden, prevpred, hbf,
                                    Wr_in, br_in, Wi_in, bi_in, Wn_in, bn_in,
                                    Wr_h, Wi_h, Wh_h,
                                    Wo1, bo1, Wo2, bo2, Wo3, bo3, out, t);
    }
}